// Round 10
// baseline (110.438 us; speedup 1.0000x reference)
//
#include <hip/hip_runtime.h>

#define N 8192
#define Dk 128
#define NC 1024
#define EPSC 1e-6f
#define MARGIN 0.2f

typedef __attribute__((ext_vector_type(8))) short bf16x8;
typedef __attribute__((ext_vector_type(16))) float f32x16;

__device__ __forceinline__ unsigned short f2bf(float f) {
    unsigned u = __float_as_uint(f);
    u = (u + 0x7FFFu + ((u >> 16) & 1u)) >> 16;  // RNE fp32->bf16
    return (unsigned short)u;
}

// ---- fused counting sort: ONE block, 1024 threads ----
__global__ void sort_kernel(const int* __restrict__ tgt, int* __restrict__ perm,
                            int* __restrict__ cls, uint2* __restrict__ band) {
    __shared__ int histS[NC], prefS[NC], curS[NC];
    int t = threadIdx.x;
    histS[t] = 0;
    __syncthreads();
    int myt[8];
#pragma unroll
    for (int k = 0; k < 8; ++k) {
        myt[k] = tgt[k * 1024 + t];
        atomicAdd(&histS[myt[k]], 1);
    }
    __syncthreads();
    int h = histS[t];
    prefS[t] = h;
    __syncthreads();
    for (int off = 1; off < NC; off <<= 1) {  // inclusive scan
        int v = (t >= off) ? prefS[t - off] : 0;
        __syncthreads();
        prefS[t] += v;
        __syncthreads();
    }
    int ex = prefS[t] - h;
    __syncthreads();
    prefS[t] = ex;  // exclusive
    curS[t] = ex;
    __syncthreads();
#pragma unroll
    for (int k = 0; k < 8; ++k) {
        int i = k * 1024 + t;
        int c = myt[k];
        int pos = atomicAdd(&curS[c], 1);
        perm[pos] = i;
        cls[pos] = c;
        uint2 b;
        b.x = (unsigned)prefS[c];
        b.y = (unsigned)(prefS[c] + histS[c]);
        band[pos] = b;
    }
}

// ---- prep: gather x[perm[k]] -> 32x32x16-fragment pack, P[k], Qh[k] = -Q/2 ----
// Frag32 uint4 index: ((k>>5)*8 + (c>>1))*64 + (c&1)*32 + (k&31), c = 8-elem chunk 0..15
// (lane&31 = row-in-tile, lane>>5 = K-8-half of the K16 slice kk=c>>1)
__global__ void prep_kernel(const float* __restrict__ x, const int* __restrict__ perm,
                            uint4* __restrict__ Frag, float* __restrict__ Qh,
                            float* __restrict__ P) {
    int wv = blockIdx.x * 4 + (threadIdx.x >> 6);
    int lane = threadIdx.x & 63;
    int k = wv * 4 + (lane >> 4);  // permuted row
    int c = lane & 15;
    int orig = perm[k];
    const float4* x4 = reinterpret_cast<const float4*>(x);
    float4 v0 = x4[orig * 32 + c * 2];
    float4 v1 = x4[orig * 32 + c * 2 + 1];
    float sq = v0.x * v0.x + v0.y * v0.y + v0.z * v0.z + v0.w * v0.w +
               v1.x * v1.x + v1.y * v1.y + v1.z * v1.z + v1.w * v1.w;
    float s = v0.x + v0.y + v0.z + v0.w + v1.x + v1.y + v1.z + v1.w;
    ushort4 lo, hi;
    lo.x = f2bf(v0.x); lo.y = f2bf(v0.y); lo.z = f2bf(v0.z); lo.w = f2bf(v0.w);
    hi.x = f2bf(v1.x); hi.y = f2bf(v1.y); hi.z = f2bf(v1.z); hi.w = f2bf(v1.w);
    uint4 pk;
    pk.x = (unsigned)lo.x | ((unsigned)lo.y << 16);
    pk.y = (unsigned)lo.z | ((unsigned)lo.w << 16);
    pk.z = (unsigned)hi.x | ((unsigned)hi.y << 16);
    pk.w = (unsigned)hi.z | ((unsigned)hi.w << 16);
    Frag[(((k >> 5) * 8) + (c >> 1)) * 64 + (c & 1) * 32 + (k & 31)] = pk;
#pragma unroll
    for (int m = 1; m <= 8; m <<= 1) {
        sq += __shfl_xor(sq, m);
        s += __shfl_xor(s, m);
    }
    if (c == 0) {
        P[k] = sq - 2.0f * EPSC * s;
        Qh[k] = -0.5f * (sq + 2.0f * EPSC * s + (float)Dk * EPSC * EPSC);
    }
}

// ---- qpack: Q/class tables in C/D reg order (row = (reg&3)+8*(reg>>2)+4*h) ----
// entry o: jt=o>>3, h=(o&7)>>2, g=o&3, base = jt*32 + 8g + 4h
__global__ void qpack_kernel(const float* __restrict__ Qh, const int* __restrict__ cls,
                             float4* __restrict__ Qpk, int4* __restrict__ Cpk,
                             float* __restrict__ out) {
    int o = blockIdx.x * 256 + threadIdx.x;  // 0..2047
    int base = (o >> 3) * 32 + (o & 3) * 8 + ((o >> 2) & 1) * 4;
    float4 qv;
    qv.x = Qh[base + 0]; qv.y = Qh[base + 1]; qv.z = Qh[base + 2]; qv.w = Qh[base + 3];
    Qpk[o] = qv;
    int4 cv;
    cv.x = cls[base + 0]; cv.y = cls[base + 1]; cv.z = cls[base + 2]; cv.w = cls[base + 3];
    Cpk[o] = cv;
    if (o == 0) out[0] = 0.0f;  // replaces the d_out memset
}

// stage tile jt0+t: 8 coalesced 1KB B-frag loads + acc init = -Q_j/2 (C-operand trick)
#define STAGE(Bx, ax, t)                                                         \
    do {                                                                         \
        const int jt_ = jt0 + (t);                                               \
        _Pragma("unroll") for (int kk = 0; kk < 8; ++kk)                         \
            Bx[kk] = Fr[(jt_ * 8 + kk) * 64 + lane];                             \
        float4 q0_ = Qpk[jt_ * 8 + 4 * h + 0];                                   \
        float4 q1_ = Qpk[jt_ * 8 + 4 * h + 1];                                   \
        float4 q2_ = Qpk[jt_ * 8 + 4 * h + 2];                                   \
        float4 q3_ = Qpk[jt_ * 8 + 4 * h + 3];                                   \
        ax = (f32x16){q0_.x, q0_.y, q0_.z, q0_.w, q1_.x, q1_.y, q1_.z, q1_.w,    \
                      q2_.x, q2_.y, q2_.z, q2_.w, q3_.x, q3_.y, q3_.z, q3_.w};   \
    } while (0)

// 8 chained 32x32x16 MFMAs: acc = X_j . X_i^T - Q_j/2 (transposed: j = M rows)
#define MFMA8(ax, Bx)                                                            \
    do {                                                                         \
        _Pragma("unroll") for (int kk = 0; kk < 8; ++kk)                         \
            ax = __builtin_amdgcn_mfma_f32_32x32x16_bf16(Bx[kk], Af[kk], ax, 0, 0, 0); \
    } while (0)

// epilogue: lane's 16 elems = 16 j's of ONE anchor (col=lane&31). Fast = 16 fmax tree.
#define EPI(ax, t)                                                               \
    do {                                                                         \
        const int jt_ = jt0 + (t);                                               \
        if (jt_ * 32 < bHi && jt_ * 32 + 32 > bLo) { /* wave-uniform band test */ \
            _Pragma("unroll") for (int g = 0; g < 4; ++g) {                      \
                int4 cj = Cpk[jt_ * 8 + 4 * h + g];                              \
                hp = fminf(hp, cj.x == myc ? ax[4 * g + 0] : INFINITY);          \
                hp = fminf(hp, cj.y == myc ? ax[4 * g + 1] : INFINITY);          \
                hp = fminf(hp, cj.z == myc ? ax[4 * g + 2] : INFINITY);          \
                hp = fminf(hp, cj.w == myc ? ax[4 * g + 3] : INFINITY);          \
                mn = fmaxf(mn, cj.x == myc ? -INFINITY : ax[4 * g + 0]);         \
                mn = fmaxf(mn, cj.y == myc ? -INFINITY : ax[4 * g + 1]);         \
                mn = fmaxf(mn, cj.z == myc ? -INFINITY : ax[4 * g + 2]);         \
                mn = fmaxf(mn, cj.w == myc ? -INFINITY : ax[4 * g + 3]);         \
            }                                                                    \
        } else {                                                                 \
            float m0_ = fmaxf(ax[0], ax[1]), m1_ = fmaxf(ax[2], ax[3]);          \
            float m2_ = fmaxf(ax[4], ax[5]), m3_ = fmaxf(ax[6], ax[7]);          \
            float m4_ = fmaxf(ax[8], ax[9]), m5_ = fmaxf(ax[10], ax[11]);        \
            float m6_ = fmaxf(ax[12], ax[13]), m7_ = fmaxf(ax[14], ax[15]);      \
            m0_ = fmaxf(m0_, m1_); m2_ = fmaxf(m2_, m3_);                        \
            m4_ = fmaxf(m4_, m5_); m6_ = fmaxf(m6_, m7_);                        \
            mn = fmaxf(mn, fmaxf(fmaxf(m0_, m2_), fmaxf(m4_, m6_)));             \
        }                                                                        \
    } while (0)

// Kernel B: 32x32x16 MFMA, transposed (j=M). NO LDS/barriers/atomics. Grid =
// 64 ig x 8 jg; block = 128 anchors (4 waves x 32) sharing a 1024-j strip
// (32 tiles). Ping-pong acc+B; EPI of tile t runs after the other tile's MFMAs.
__global__ __launch_bounds__(256, 2) void main_kernel(
        const uint4* __restrict__ Frag, const float4* __restrict__ Qpk,
        const int4* __restrict__ Cpk, const int* __restrict__ cls,
        const uint2* __restrict__ band,
        float* __restrict__ partHp, float* __restrict__ partMn) {
    const int lane = threadIdx.x & 63;
    const int w = threadIdx.x >> 6;
    const int nn = lane & 31;
    const int h = lane >> 5;

    const int ig = (int)blockIdx.x >> 3;  // 0..63
    const int jg = (int)blockIdx.x & 7;   // 0..7
    const int rw = ig * 128 + 32 * w;     // wave's 32 anchors
    const int jt0 = jg * 32;              // strip start (32-j tile units)

    const bf16x8* Fr = reinterpret_cast<const bf16x8*>(Frag);

    const int bLo = (int)band[rw].x;
    const int bHi = (int)band[rw + 31].y;
    const int myc = cls[rw + nn];  // lane's single anchor class

    // Persistent anchor fragments: 32 rows x K128 = 8 frags (32 VGPRs)
    bf16x8 Af[8];
#pragma unroll
    for (int kk = 0; kk < 8; ++kk) Af[kk] = Fr[((rw >> 5) * 8 + kk) * 64 + lane];

    float hp = INFINITY;   // min acc over same-class
    float mn = -INFINITY;  // max acc over diff-class

    bf16x8 B0[8], B1[8];
    f32x16 a0, a1;

    STAGE(B0, a0, 0);
    STAGE(B1, a1, 1);
#pragma unroll
    for (int t = 0; t < 32; t += 2) {
        MFMA8(a0, B0);  // tile t
        MFMA8(a1, B1);  // tile t+1
        EPI(a0, t);     // runs while a1's MFMAs drain
        if (t + 2 < 32) STAGE(B0, a0, t + 2);
        EPI(a1, t + 1);
        if (t + 3 < 32) STAGE(B1, a1, t + 3);
    }

    // combine the two K... j-halves (lane ^ 32 holds same anchor, other 4h offset)
    hp = fminf(hp, __shfl_xor(hp, 32));
    mn = fmaxf(mn, __shfl_xor(mn, 32));
    if (h == 0) {  // lanes 0..31: one coalesced store per stat
        partHp[jg * N + rw + nn] = hp;
        partMn[jg * N + rw + nn] = mn;
    }
}

// ---- finish: reduce 8 strip-partials per permuted row, loss, mean ----
__global__ void finish_kernel(const float* __restrict__ P,
                              const float* __restrict__ partHp,
                              const float* __restrict__ partMn,
                              float* __restrict__ out) {
    int i = blockIdx.x * 256 + threadIdx.x;
    float hpm = INFINITY, mnm = -INFINITY;
#pragma unroll
    for (int wg = 0; wg < 8; ++wg) {
        hpm = fminf(hpm, partHp[wg * N + i]);
        mnm = fmaxf(mnm, partMn[wg * N + i]);
    }
    float Pi = P[i];
    float hp = sqrtf(fmaxf(fmaf(-2.0f, hpm, Pi), 0.0f));
    float hn = sqrtf(fmaxf(fmaf(-2.0f, mnm, Pi), 0.0f));
    float sum = fmaxf(hp - hn + MARGIN, 0.0f) * (1.0f / (float)N);
#pragma unroll
    for (int m = 32; m >= 1; m >>= 1) sum += __shfl_xor(sum, m);
    __shared__ float ws[4];
    int lane = threadIdx.x & 63, wv = threadIdx.x >> 6;
    if (lane == 0) ws[wv] = sum;
    __syncthreads();
    if (threadIdx.x == 0) atomicAdd(out, ws[0] + ws[1] + ws[2] + ws[3]);
}

extern "C" void kernel_launch(void* const* d_in, const int* in_sizes, int n_in,
                              void* d_out, int out_size, void* d_ws, size_t ws_size,
                              hipStream_t stream) {
    const float* x = (const float*)d_in[0];
    const int* tgt = (const int*)d_in[1];
    float* out = (float*)d_out;

    char* ws = (char*)d_ws;
    size_t off = 0;
    uint4* Frag = (uint4*)(ws + off); off += (size_t)N * Dk * 2;    // 2 MB
    float* Qh = (float*)(ws + off); off += (size_t)N * 4;
    float* P = (float*)(ws + off); off += (size_t)N * 4;
    float4* Qpk = (float4*)(ws + off); off += (size_t)2048 * 16;
    int4* Cpk = (int4*)(ws + off); off += (size_t)2048 * 16;
    float* partHp = (float*)(ws + off); off += (size_t)8 * N * 4;   // 256 KB
    float* partMn = (float*)(ws + off); off += (size_t)8 * N * 4;   // 256 KB
    uint2* band = (uint2*)(ws + off); off += (size_t)N * 8;
    int* perm = (int*)(ws + off); off += (size_t)N * 4;
    int* cls = (int*)(ws + off); off += (size_t)N * 4;

    sort_kernel<<<1, 1024, 0, stream>>>(tgt, perm, cls, band);
    prep_kernel<<<N / 16, 256, 0, stream>>>(x, perm, Frag, Qh, P);
    qpack_kernel<<<8, 256, 0, stream>>>(Qh, cls, Qpk, Cpk, out);
    main_kernel<<<512, 256, 0, stream>>>(Frag, Qpk, Cpk, cls, band, partHp, partMn);
    finish_kernel<<<32, 256, 0, stream>>>(P, partHp, partMn, out);
}